// Round 6
// baseline (189.227 us; speedup 1.0000x reference)
//
#include <hip/hip_runtime.h>

#define NNODES 196608
#define NH 9
#define F 64
#define K_TOT 576      // NH * F
#define KSTEPS 18      // K_TOT / 32
#define LN_EPS 1e-5f

typedef __attribute__((ext_vector_type(8))) short short8v;
typedef __attribute__((ext_vector_type(4))) float f32x4;

__device__ __forceinline__ unsigned short f2bf(float f) {
    unsigned int u = __float_as_uint(f);
    u += 0x7fff + ((u >> 16) & 1);          // round-to-nearest-even
    return (unsigned short)(u >> 16);
}
__device__ __forceinline__ float silu_f(float z) { return z / (1.0f + __expf(-z)); }

// Async global->LDS, 16 B per lane. Dest is wave-uniform base + lane*16 (linear).
__device__ __forceinline__ void gload_lds16(const void* g, void* l) {
    __builtin_amdgcn_global_load_lds((__attribute__((address_space(1))) void*)g,
                                     (__attribute__((address_space(3))) void*)l,
                                     16, 0, 0);
}

// Build bf16 transposed weights Wt[o][k] (k = head*64 + f) from f32 W[head][f][o].
__global__ __launch_bounds__(256) void prep_wt(const float* __restrict__ W1,
                                               const float* __restrict__ W2,
                                               unsigned short* __restrict__ Wt1,
                                               unsigned short* __restrict__ Wt2) {
    int tid = blockIdx.x * 256 + threadIdx.x;
    if (tid >= F * K_TOT) return;
    int k = tid % K_TOT, o = tid / K_TOT;
    Wt1[tid] = f2bf(W1[(size_t)k * F + o]);
    Wt2[tid] = f2bf(W2[(size_t)k * F + o]);
}

// LN + SiLU, f32 in -> bf16 out. 16 threads per row, float4 per thread.
__global__ __launch_bounds__(256) void ln1_silu(const float* __restrict__ x,
                                                const float* __restrict__ w,
                                                const float* __restrict__ b,
                                                unsigned short* __restrict__ out) {
    const int t = threadIdx.x;
    const int row = blockIdx.x * 16 + (t >> 4);
    const int fl = (t & 15) * 4;
    const float4 v = *(const float4*)(x + (size_t)row * F + fl);
    float s = v.x + v.y + v.z + v.w;
    float ss = v.x * v.x + v.y * v.y + v.z * v.z + v.w * v.w;
#pragma unroll
    for (int o = 8; o; o >>= 1) { s += __shfl_xor(s, o); ss += __shfl_xor(ss, o); }
    const float mu = s * (1.0f / F);
    const float rstd = rsqrtf(ss * (1.0f / F) - mu * mu + LN_EPS);
    const float4 wv = *(const float4*)(w + fl);
    const float4 bv = *(const float4*)(b + fl);
    ushort4 o4;
    o4.x = f2bf(silu_f((v.x - mu) * rstd * wv.x + bv.x));
    o4.y = f2bf(silu_f((v.y - mu) * rstd * wv.y + bv.y));
    o4.z = f2bf(silu_f((v.z - mu) * rstd * wv.z + bv.z));
    o4.w = f2bf(silu_f((v.w - mu) * rstd * wv.w + bv.w));
    *(ushort4*)(out + (size_t)row * F + fl) = o4;
}

// Block = 64 nodes, 4 waves; gathered rows staged ONCE per block into
// double-buffered LDS via global_load_lds; XOR-swizzle (chunk^(row&7)) applied on
// BOTH the per-lane global source and the ds_read address (rule #21) -> 0 conflicts.
// Round-5 lesson: __syncthreads drains vmcnt(0), so intra-block prefetch depth is
// structurally 1 -> latency must be hidden by INDEPENDENT BLOCKS. waves_per_eu(3,3)
// was capping that at 3 blocks/CU; launch_bounds(256,6) -> 6 blocks/CU (LDS 17.4KB
// allows 9, VGPR cap 85 vs measured 68).
template<int FINAL>
__global__ __launch_bounds__(256, 6)
void gconv_mfma(
    const unsigned short* __restrict__ h,
    const int* __restrict__ adjc,
    const unsigned short* __restrict__ Wt,
    const float* __restrict__ bias,
    const float* __restrict__ lnw, const float* __restrict__ lnb,
    const float* __restrict__ xres,
    void* __restrict__ outv)
{
    __shared__ __align__(16) char smem[64 * 68 * 4];   // 17408 B; tiles use first 16384
    unsigned short* tile = (unsigned short*)smem;       // [2][64][64] bf16
    float (*T)[68] = (float (*)[68])smem;               // epilogue reuse (after barrier)

    const int wave = threadIdx.x >> 6;
    const int lane = threadIdx.x & 63;
    const int l16 = lane & 15, lg = lane >> 4;
    const int nodeBase = blockIdx.x * 64;

    // Staging geometry: instr j (=2w, 2w+1) covers rows 8j..8j+7, 8 chunks of 16 B.
    const int srow = lane >> 3;              // row within group of 8 (== row&7)
    const int sswz = (lane & 7) ^ srow;      // pre-swizzled global chunk for this lane
    const int rA = wave * 16 + srow;
    const int rB = rA + 8;

    int idxA[NH], idxB[NH];
    {
        const int* a0 = adjc + (size_t)(nodeBase + rA) * NH;
        const int* a1 = adjc + (size_t)(nodeBase + rB) * NH;
#pragma unroll
        for (int hh = 0; hh < NH; ++hh) { idxA[hh] = a0[hh]; idxB[hh] = a1[hh]; }
    }

    // B fragments: lane holds o = 16*wave + l16, k = 32*s + lg*8 + [0..7]
    short8v bfrag[KSTEPS];
    {
        const unsigned short* wr = Wt + (size_t)(wave * 16 + l16) * K_TOT + lg * 8;
#pragma unroll
        for (int s = 0; s < KSTEPS; ++s) bfrag[s] = *(const short8v*)(wr + s * 32);
    }

    f32x4 acc[4];
#pragma unroll
    for (int m = 0; m < 4; ++m) acc[m] = (f32x4){0.f, 0.f, 0.f, 0.f};

#define STAGE(BUF, HH)                                                         \
    do {                                                                       \
        gload_lds16(h + (size_t)idxA[HH] * F + sswz * 8,                       \
                    (char*)tile + (BUF) * 8192 + (2 * wave) * 1024);           \
        gload_lds16(h + (size_t)idxB[HH] * F + sswz * 8,                       \
                    (char*)tile + (BUF) * 8192 + (2 * wave + 1) * 1024);       \
    } while (0)

#define COMPUTE(BUF, HH)                                                       \
    _Pragma("unroll")                                                          \
    for (int m = 0; m < 4; ++m) {                                              \
        _Pragma("unroll")                                                      \
        for (int kh = 0; kh < 2; ++kh) {                                       \
            const short8v a = *(const short8v*)((char*)tile + (BUF) * 8192     \
                + (m * 16 + l16) * 128 + (((kh * 4 + lg) ^ (l16 & 7)) * 16));  \
            acc[m] = __builtin_amdgcn_mfma_f32_16x16x32_bf16(                  \
                a, bfrag[(HH) * 2 + kh], acc[m], 0, 0, 0);                     \
        }                                                                      \
    }

    STAGE(0, 0);
    __syncthreads();
#pragma unroll
    for (int hh = 0; hh < NH; ++hh) {
        if (hh < NH - 1) STAGE((hh + 1) & 1, hh + 1);   // issue next head first
        COMPUTE(hh & 1, hh);                            // overlap with in-flight stage
        __syncthreads();                                // drain + swap
    }
#undef STAGE
#undef COMPUTE

    // Epilogue: transpose via LDS (reuses tile region; last barrier above covers it).
    // D layout: row(node) = m*16 + lg*4 + r, col(o) = wave*16 + l16
#pragma unroll
    for (int m = 0; m < 4; ++m)
#pragma unroll
        for (int r = 0; r < 4; ++r)
            T[m * 16 + lg * 4 + r][wave * 16 + l16] = acc[m][r];
    __syncthreads();

    const int t = threadIdx.x;
    const int nl = t >> 2, q = t & 3;                // 4 threads per node, 16 outputs each
    const int node = nodeBase + nl;
    float v[16];
#pragma unroll
    for (int i = 0; i < 16; ++i) v[i] = T[nl][q * 16 + i] + bias[q * 16 + i];

    if (FINAL) {
        float* out = (float*)outv;
#pragma unroll
        for (int i4 = 0; i4 < 4; ++i4) {
            const float4 xr = *(const float4*)(xres + (size_t)node * F + q * 16 + i4 * 4);
            float4 ov;
            ov.x = v[i4 * 4 + 0] + xr.x; ov.y = v[i4 * 4 + 1] + xr.y;
            ov.z = v[i4 * 4 + 2] + xr.z; ov.w = v[i4 * 4 + 3] + xr.w;
            *(float4*)(out + (size_t)node * F + q * 16 + i4 * 4) = ov;
        }
    } else {
        float s = 0.f, ss = 0.f;
#pragma unroll
        for (int i = 0; i < 16; ++i) { s += v[i]; ss += v[i] * v[i]; }
        s += __shfl_xor(s, 1); ss += __shfl_xor(ss, 1);
        s += __shfl_xor(s, 2); ss += __shfl_xor(ss, 2);
        const float mu = s * (1.0f / F);
        const float rstd = rsqrtf(ss * (1.0f / F) - mu * mu + LN_EPS);
        unsigned short* out = (unsigned short*)outv;
        unsigned short ob[16];
#pragma unroll
        for (int i = 0; i < 16; ++i) {
            const int o = q * 16 + i;
            const float y = (v[i] - mu) * rstd * lnw[o] + lnb[o];
            ob[i] = f2bf(silu_f(y));
        }
#pragma unroll
        for (int c = 0; c < 2; ++c)
            *(short8v*)(out + (size_t)node * F + q * 16 + c * 8) = *(short8v*)(ob + c * 8);
    }
}

extern "C" void kernel_launch(void* const* d_in, const int* in_sizes, int n_in,
                              void* d_out, int out_size, void* d_ws, size_t ws_size,
                              hipStream_t stream)
{
    const float* x    = (const float*)d_in[0];
    const int*   adjc = (const int*)d_in[1];
    const float* ln1w = (const float*)d_in[2];
    const float* ln1b = (const float*)d_in[3];
    const float* W1   = (const float*)d_in[4];
    const float* b1   = (const float*)d_in[5];
    const float* ln2w = (const float*)d_in[6];
    const float* ln2b = (const float*)d_in[7];
    const float* W2   = (const float*)d_in[8];
    const float* b2   = (const float*)d_in[9];
    float* out = (float*)d_out;

    unsigned short* h1  = (unsigned short*)d_ws;              // 25.2 MB bf16
    unsigned short* h2  = h1 + (size_t)NNODES * F;            // 25.2 MB bf16
    unsigned short* Wt1 = h2 + (size_t)NNODES * F;            // 144 KB
    unsigned short* Wt2 = Wt1 + F * K_TOT;                    // 144 KB

    prep_wt<<<(F * K_TOT + 255) / 256, 256, 0, stream>>>(W1, W2, Wt1, Wt2);
    ln1_silu<<<NNODES / 16, 256, 0, stream>>>(x, ln1w, ln1b, h1);
    gconv_mfma<0><<<NNODES / 64, 256, 0, stream>>>(h1, adjc, Wt1, b1, ln2w, ln2b, nullptr, h2);
    gconv_mfma<1><<<NNODES / 64, 256, 0, stream>>>(h2, adjc, Wt2, b2, nullptr, nullptr, x, out);
}

// Round 7
// 122.593 us; speedup vs baseline: 1.5435x; 1.5435x over previous
//
#include <hip/hip_runtime.h>

#define NNODES 196608
#define NH 9
#define F 64
#define K_TOT 576      // NH * F
#define KSTEPS 18      // K_TOT / 32
#define LN_EPS 1e-5f

typedef __attribute__((ext_vector_type(8))) short short8v;
typedef __attribute__((ext_vector_type(4))) float f32x4;

__device__ __forceinline__ unsigned short f2bf(float f) {
    unsigned int u = __float_as_uint(f);
    u += 0x7fff + ((u >> 16) & 1);          // round-to-nearest-even
    return (unsigned short)(u >> 16);
}
__device__ __forceinline__ float silu_f(float z) { return z / (1.0f + __expf(-z)); }

// Async global->LDS, 16 B per lane. Dest is wave-uniform base + lane*16 (linear).
__device__ __forceinline__ void gload_lds16(const void* g, void* l) {
    __builtin_amdgcn_global_load_lds((__attribute__((address_space(1))) void*)g,
                                     (__attribute__((address_space(3))) void*)l,
                                     16, 0, 0);
}

// Build bf16 transposed weights Wt[o][k] (k = head*64 + f) from f32 W[head][f][o].
__global__ __launch_bounds__(256) void prep_wt(const float* __restrict__ W1,
                                               const float* __restrict__ W2,
                                               unsigned short* __restrict__ Wt1,
                                               unsigned short* __restrict__ Wt2) {
    int tid = blockIdx.x * 256 + threadIdx.x;
    if (tid >= F * K_TOT) return;
    int k = tid % K_TOT, o = tid / K_TOT;
    Wt1[tid] = f2bf(W1[(size_t)k * F + o]);
    Wt2[tid] = f2bf(W2[(size_t)k * F + o]);
}

// LN + SiLU, f32 in -> bf16 out. 16 threads per row, float4 per thread.
__global__ __launch_bounds__(256) void ln1_silu(const float* __restrict__ x,
                                                const float* __restrict__ w,
                                                const float* __restrict__ b,
                                                unsigned short* __restrict__ out) {
    const int t = threadIdx.x;
    const int row = blockIdx.x * 16 + (t >> 4);
    const int fl = (t & 15) * 4;
    const float4 v = *(const float4*)(x + (size_t)row * F + fl);
    float s = v.x + v.y + v.z + v.w;
    float ss = v.x * v.x + v.y * v.y + v.z * v.z + v.w * v.w;
#pragma unroll
    for (int o = 8; o; o >>= 1) { s += __shfl_xor(s, o); ss += __shfl_xor(ss, o); }
    const float mu = s * (1.0f / F);
    const float rstd = rsqrtf(ss * (1.0f / F) - mu * mu + LN_EPS);
    const float4 wv = *(const float4*)(w + fl);
    const float4 bv = *(const float4*)(b + fl);
    ushort4 o4;
    o4.x = f2bf(silu_f((v.x - mu) * rstd * wv.x + bv.x));
    o4.y = f2bf(silu_f((v.y - mu) * rstd * wv.y + bv.y));
    o4.z = f2bf(silu_f((v.z - mu) * rstd * wv.z + bv.z));
    o4.w = f2bf(silu_f((v.w - mu) * rstd * wv.w + bv.w));
    *(ushort4*)(out + (size_t)row * F + fl) = o4;
}

// Block = 64 nodes, 4 waves; gathered rows staged ONCE per block via global_load_lds,
// XOR-swizzled on both the global source and the ds_read address (rule #21).
// Round-6 lesson: forcing 6 blocks/CU spilled (40 VGPR + 86MB scratch writes) and
// REGRESSED -> occupancy and register residency are the same knob here. Instead:
// depth via TRIPLE-buffered LDS + counted vmcnt (T4). Per head: wave issues 2
// gload_lds; loop = { s_waitcnt vmcnt(2) [stage(h) done, stage(h+1) in flight]
// -> s_barrier -> STAGE(h+2) -> COMPUTE(h) }. vmcnt(2) cannot under-wait: stage(h)
// ops are older than stage(h+1)'s two, and compiler loads are consumed (-> complete)
// before the wait. Buf reuse safe: barrier(h) orders all waves' compute(h-1)
// (ds_reads consumed by MFMAs pre-barrier) before stage(h+2) overwrites buf((h-1)%3).
template<int FINAL>
__global__ __launch_bounds__(256) __attribute__((amdgpu_waves_per_eu(3, 4)))
void gconv_mfma(
    const unsigned short* __restrict__ h,
    const int* __restrict__ adjc,
    const unsigned short* __restrict__ Wt,
    const float* __restrict__ bias,
    const float* __restrict__ lnw, const float* __restrict__ lnb,
    const float* __restrict__ xres,
    void* __restrict__ outv)
{
    __shared__ __align__(16) char smem[3 * 8192];       // 24 KB: 3 A-tile buffers
    unsigned short* tile = (unsigned short*)smem;        // [3][64 rows][64] bf16
    float (*T)[68] = (float (*)[68])smem;                // epilogue reuse (17.4 KB)

    const int wave = threadIdx.x >> 6;
    const int lane = threadIdx.x & 63;
    const int l16 = lane & 15, lg = lane >> 4;
    const int nodeBase = blockIdx.x * 64;

    // Staging geometry: instr j (=2w, 2w+1) covers rows 8j..8j+7, 8 chunks of 16 B.
    const int srow = lane >> 3;              // row within group of 8 (== row&7)
    const int sswz = (lane & 7) ^ srow;      // pre-swizzled global chunk for this lane
    const int rA = wave * 16 + srow;
    const int rB = rA + 8;

    int idxA[NH], idxB[NH];
    {
        const int* a0 = adjc + (size_t)(nodeBase + rA) * NH;
        const int* a1 = adjc + (size_t)(nodeBase + rB) * NH;
#pragma unroll
        for (int hh = 0; hh < NH; ++hh) { idxA[hh] = a0[hh]; idxB[hh] = a1[hh]; }
    }

    // B fragments: lane holds o = 16*wave + l16, k = 32*s + lg*8 + [0..7]
    short8v bfrag[KSTEPS];
    {
        const unsigned short* wr = Wt + (size_t)(wave * 16 + l16) * K_TOT + lg * 8;
#pragma unroll
        for (int s = 0; s < KSTEPS; ++s) bfrag[s] = *(const short8v*)(wr + s * 32);
    }

    f32x4 acc[4];
#pragma unroll
    for (int m = 0; m < 4; ++m) acc[m] = (f32x4){0.f, 0.f, 0.f, 0.f};

#define STAGE(BUF, HH)                                                         \
    do {                                                                       \
        gload_lds16(h + (size_t)idxA[HH] * F + sswz * 8,                       \
                    (char*)tile + (BUF) * 8192 + (2 * wave) * 1024);           \
        gload_lds16(h + (size_t)idxB[HH] * F + sswz * 8,                       \
                    (char*)tile + (BUF) * 8192 + (2 * wave + 1) * 1024);       \
    } while (0)

#define COMPUTE(BUF, HH)                                                       \
    _Pragma("unroll")                                                          \
    for (int m = 0; m < 4; ++m) {                                              \
        _Pragma("unroll")                                                      \
        for (int kh = 0; kh < 2; ++kh) {                                       \
            const short8v a = *(const short8v*)((char*)tile + (BUF) * 8192     \
                + (m * 16 + l16) * 128 + (((kh * 4 + lg) ^ (l16 & 7)) * 16));  \
            acc[m] = __builtin_amdgcn_mfma_f32_16x16x32_bf16(                  \
                a, bfrag[(HH) * 2 + kh], acc[m], 0, 0, 0);                     \
        }                                                                      \
    }

    STAGE(0, 0);
    STAGE(1, 1);
#pragma unroll
    for (int hh = 0; hh < NH; ++hh) {
        if (hh < NH - 1) { asm volatile("s_waitcnt vmcnt(2)" ::: "memory"); }
        else             { asm volatile("s_waitcnt vmcnt(0)" ::: "memory"); }
        __builtin_amdgcn_s_barrier();
        if (hh < NH - 2) STAGE((hh + 2) % 3, hh + 2);   // issue early: 2 phases of cover
        COMPUTE(hh % 3, hh);
    }
#undef STAGE
#undef COMPUTE

    __syncthreads();   // all compute reads done before tile region is reused as T

    // Epilogue: transpose via LDS. D layout: row(node)=m*16+lg*4+r, col(o)=wave*16+l16
#pragma unroll
    for (int m = 0; m < 4; ++m)
#pragma unroll
        for (int r = 0; r < 4; ++r)
            T[m * 16 + lg * 4 + r][wave * 16 + l16] = acc[m][r];
    __syncthreads();

    const int t = threadIdx.x;
    const int nl = t >> 2, q = t & 3;                // 4 threads per node, 16 outputs each
    const int node = nodeBase + nl;
    float v[16];
#pragma unroll
    for (int i = 0; i < 16; ++i) v[i] = T[nl][q * 16 + i] + bias[q * 16 + i];

    if (FINAL) {
        float* out = (float*)outv;
#pragma unroll
        for (int i4 = 0; i4 < 4; ++i4) {
            const float4 xr = *(const float4*)(xres + (size_t)node * F + q * 16 + i4 * 4);
            float4 ov;
            ov.x = v[i4 * 4 + 0] + xr.x; ov.y = v[i4 * 4 + 1] + xr.y;
            ov.z = v[i4 * 4 + 2] + xr.z; ov.w = v[i4 * 4 + 3] + xr.w;
            *(float4*)(out + (size_t)node * F + q * 16 + i4 * 4) = ov;
        }
    } else {
        float s = 0.f, ss = 0.f;
#pragma unroll
        for (int i = 0; i < 16; ++i) { s += v[i]; ss += v[i] * v[i]; }
        s += __shfl_xor(s, 1); ss += __shfl_xor(ss, 1);
        s += __shfl_xor(s, 2); ss += __shfl_xor(ss, 2);
        const float mu = s * (1.0f / F);
        const float rstd = rsqrtf(ss * (1.0f / F) - mu * mu + LN_EPS);
        unsigned short* out = (unsigned short*)outv;
        unsigned short ob[16];
#pragma unroll
        for (int i = 0; i < 16; ++i) {
            const int o = q * 16 + i;
            const float y = (v[i] - mu) * rstd * lnw[o] + lnb[o];
            ob[i] = f2bf(silu_f(y));
        }
#pragma unroll
        for (int c = 0; c < 2; ++c)
            *(short8v*)(out + (size_t)node * F + q * 16 + c * 8) = *(short8v*)(ob + c * 8);
    }
}

extern "C" void kernel_launch(void* const* d_in, const int* in_sizes, int n_in,
                              void* d_out, int out_size, void* d_ws, size_t ws_size,
                              hipStream_t stream)
{
    const float* x    = (const float*)d_in[0];
    const int*   adjc = (const int*)d_in[1];
    const float* ln1w = (const float*)d_in[2];
    const float* ln1b = (const float*)d_in[3];
    const float* W1   = (const float*)d_in[4];
    const float* b1   = (const float*)d_in[5];
    const float* ln2w = (const float*)d_in[6];
    const float* ln2b = (const float*)d_in[7];
    const float* W2   = (const float*)d_in[8];
    const float* b2   = (const float*)d_in[9];
    float* out = (float*)d_out;

    unsigned short* h1  = (unsigned short*)d_ws;              // 25.2 MB bf16
    unsigned short* h2  = h1 + (size_t)NNODES * F;            // 25.2 MB bf16
    unsigned short* Wt1 = h2 + (size_t)NNODES * F;            // 144 KB
    unsigned short* Wt2 = Wt1 + F * K_TOT;                    // 144 KB

    prep_wt<<<(F * K_TOT + 255) / 256, 256, 0, stream>>>(W1, W2, Wt1, Wt2);
    ln1_silu<<<NNODES / 16, 256, 0, stream>>>(x, ln1w, ln1b, h1);
    gconv_mfma<0><<<NNODES / 64, 256, 0, stream>>>(h1, adjc, Wt1, b1, ln2w, ln2b, nullptr, h2);
    gconv_mfma<1><<<NNODES / 64, 256, 0, stream>>>(h2, adjc, Wt2, b2, nullptr, nullptr, x, out);
}